// Round 3
// baseline (550.043 us; speedup 1.0000x reference)
//
#include <hip/hip_runtime.h>
#include <hip/hip_cooperative_groups.h>
#include <math.h>

namespace cg = cooperative_groups;

#define B 32
#define D 512
#define H 1024
#define G4 4096      // 4*H
#define PCH 32       // plastic i-chunks (32 i each)  -> B*PCH = 1024 units
#define GCH 48       // gate i-chunks of 32: 32 cover h (1024), 16 cover x (512); 16*48=768 units
#define NBLK 1024    // cooperative grid: 4 blocks/CU on 256 CUs

typedef float f4v __attribute__((ext_vector_type(4)));

// ---------------------------------------------------------------------------
// Phase 1: plastic partials (all 1024 blocks) + gate partials (blocks 0..767).
__device__ __forceinline__ void phase_partials(
    int blk, int tid,
    const float* __restrict__ x, const float* __restrict__ h0,
    const float* __restrict__ wh, const float* __restrict__ wx,
    const float* __restrict__ alpha, const float* __restrict__ hebb,
    float* __restrict__ gp, float* __restrict__ pp) {
  // ---- plastic unit: pp[c][b][h] = sum_{i in chunk} h0*alpha*Hebb0 ----
  {
    int b = blk >> 5;          // / PCH
    int c = blk & (PCH - 1);
    int h4 = tid * 4;
    int i0 = c * (H / PCH);
    const float* hb = hebb + (size_t)b * H * H;
    float4 acc = make_float4(0.f, 0.f, 0.f, 0.f);
#pragma unroll 8
    for (int i = i0; i < i0 + (H / PCH); ++i) {
      float hv = h0[b * H + i];                       // wave-uniform -> sgpr
      float4 a = *(const float4*)(alpha + (size_t)i * H + h4);
      float4 e = *(const float4*)(hb + (size_t)i * H + h4);
      acc.x += hv * a.x * e.x;
      acc.y += hv * a.y * e.y;
      acc.z += hv * a.z * e.z;
      acc.w += hv * a.w * e.w;
    }
    *(float4*)(pp + ((size_t)c * B + b) * H + h4) = acc;
  }
  // ---- gate unit: gp[c][b][j] = sum_{i in chunk c} in[b,i]*W[i,j] ----
  if (blk < 16 * GCH) {
    int c = blk % GCH;
    int j = (blk / GCH) * 256 + tid;
    float acc[B];
#pragma unroll
    for (int b2 = 0; b2 < B; ++b2) acc[b2] = 0.f;
    if (c < 32) {
      int i0 = c * 32;
#pragma unroll 8
      for (int i = i0; i < i0 + 32; ++i) {
        float w = wh[(size_t)i * G4 + j];
#pragma unroll
        for (int b2 = 0; b2 < B; ++b2) acc[b2] += h0[b2 * H + i] * w;
      }
    } else {
      int i0 = (c - 32) * 32;
#pragma unroll 8
      for (int i = i0; i < i0 + 32; ++i) {
        float w = wx[(size_t)i * G4 + j];
#pragma unroll
        for (int b2 = 0; b2 < B; ++b2) acc[b2] += x[b2 * D + i] * w;
      }
    }
#pragma unroll
    for (int b2 = 0; b2 < B; ++b2) gp[((size_t)c * B + b2) * G4 + j] = acc[b2];
  }
}

// ---------------------------------------------------------------------------
// Phase 2: reduce partials + activations (blocks 0..127; one thread per (b,h)).
__device__ __forceinline__ void phase_combine(
    int blk, int tid,
    const float* __restrict__ gp, const float* __restrict__ pp,
    const float* __restrict__ bias, const float* __restrict__ c0,
    float* __restrict__ out, float* __restrict__ tg) {
  int t = blk * 256 + tid;      // 0..B*H-1
  int b = t >> 10;
  int h = t & (H - 1);
  float sf = bias[h], si = bias[H + h], so = bias[2 * H + h], sg = bias[3 * H + h];
#pragma unroll 8
  for (int c = 0; c < GCH; ++c) {
    const float* g = gp + ((size_t)c * B + b) * G4;
    sf += g[h];
    si += g[H + h];
    so += g[2 * H + h];
    sg += g[3 * H + h];
  }
#pragma unroll 8
  for (int c = 0; c < PCH; ++c) sg += pp[((size_t)c * B + b) * H + h];
  float fg = 1.f / (1.f + expf(-sf));
  float ig = 1.f / (1.f + expf(-si));
  float og = 1.f / (1.f + expf(-so));
  float tgv = tanhf(sg);
  float c1 = fg * c0[t] + ig * tgv;
  float h1 = og * tanhf(c1);
  out[t] = h1;                 // h1 block
  out[B * H + t] = c1;         // c1 block
  tg[t] = tgv;
}

// ---------------------------------------------------------------------------
// Phase 3: Hebb1[b,h,i] = clip(Hebb0 + eta*h0[b,h]*tg[b,i]); 4 row-groups/block.
__device__ __forceinline__ void phase_hebb(
    int blk, int tid,
    const float* __restrict__ hebb, const float* __restrict__ h0,
    const float* __restrict__ tg, const float* __restrict__ eta,
    float* __restrict__ hout) {
  float e = eta[0];
  int t4 = tid * 4;
#pragma unroll
  for (int k = 0; k < 4; ++k) {
    int unit = blk * 4 + k;      // 0..4095
    int b = unit >> 7;
    int hg = unit & 127;         // group of 8 h-rows
    float4 tv = *(const float4*)(tg + b * H + t4);
    size_t base = ((size_t)b * H + (size_t)hg * 8) * H + t4;
    const float* src = hebb + base;
    float* dst = hout + base;
#pragma unroll
    for (int r = 0; r < 8; ++r) {
      float s = e * h0[b * H + hg * 8 + r];   // wave-uniform scalar
      float4 v = *(const float4*)(src + (size_t)r * H);
      f4v rr;
      rr.x = fminf(fmaxf(v.x + s * tv.x, -1.f), 1.f);
      rr.y = fminf(fmaxf(v.y + s * tv.y, -1.f), 1.f);
      rr.z = fminf(fmaxf(v.z + s * tv.z, -1.f), 1.f);
      rr.w = fminf(fmaxf(v.w + s * tv.w, -1.f), 1.f);
      __builtin_nontemporal_store(rr, (f4v*)(dst + (size_t)r * H));
    }
  }
}

// ---------------------------------------------------------------------------
// Cooperative mega-kernel: one dispatch, two grid syncs.
__global__ __launch_bounds__(256, 4) void k_coop(
    const float* __restrict__ x, const float* __restrict__ h0,
    const float* __restrict__ c0, const float* __restrict__ hebb,
    const float* __restrict__ wh, const float* __restrict__ wx,
    const float* __restrict__ bias, const float* __restrict__ alpha,
    const float* __restrict__ eta,
    float* __restrict__ out, float* __restrict__ hout,
    float* __restrict__ pp, float* __restrict__ gp, float* __restrict__ tg) {
  int blk = blockIdx.x;
  int tid = threadIdx.x;
  phase_partials(blk, tid, x, h0, wh, wx, alpha, hebb, gp, pp);
  cg::this_grid().sync();
  if (blk < (B * H) / 256) phase_combine(blk, tid, gp, pp, bias, c0, out, tg);
  cg::this_grid().sync();
  phase_hebb(blk, tid, hebb, h0, tg, eta, hout);
}

// ---- fallback plain kernels (identical math) ------------------------------
__global__ __launch_bounds__(256, 4) void k_p1(
    const float* __restrict__ x, const float* __restrict__ h0,
    const float* __restrict__ wh, const float* __restrict__ wx,
    const float* __restrict__ alpha, const float* __restrict__ hebb,
    float* __restrict__ gp, float* __restrict__ pp) {
  phase_partials(blockIdx.x, threadIdx.x, x, h0, wh, wx, alpha, hebb, gp, pp);
}
__global__ __launch_bounds__(256) void k_p2(
    const float* __restrict__ gp, const float* __restrict__ pp,
    const float* __restrict__ bias, const float* __restrict__ c0,
    float* __restrict__ out, float* __restrict__ tg) {
  phase_combine(blockIdx.x, threadIdx.x, gp, pp, bias, c0, out, tg);
}
__global__ __launch_bounds__(256, 4) void k_p3(
    const float* __restrict__ hebb, const float* __restrict__ h0,
    const float* __restrict__ tg, const float* __restrict__ eta,
    float* __restrict__ hout) {
  phase_hebb(blockIdx.x, threadIdx.x, hebb, h0, tg, eta, hout);
}

extern "C" void kernel_launch(void* const* d_in, const int* in_sizes, int n_in,
                              void* d_out, int out_size, void* d_ws, size_t ws_size,
                              hipStream_t stream) {
  const float* x     = (const float*)d_in[0];
  const float* h0    = (const float*)d_in[1];
  const float* c0    = (const float*)d_in[2];
  const float* hebb  = (const float*)d_in[3];
  const float* wh    = (const float*)d_in[4];
  const float* wx    = (const float*)d_in[5];
  const float* bias  = (const float*)d_in[6];
  const float* alpha = (const float*)d_in[7];
  const float* eta   = (const float*)d_in[8];
  float* out  = (float*)d_out;
  float* hout = out + 2 * B * H;
  float* ws   = (float*)d_ws;

  float* pp = ws;                          // [PCH][B][H]   = 1,048,576 floats (4 MB)
  float* gp = pp + (size_t)PCH * B * H;    // [GCH][B][4H]  = 6,291,456 floats (25 MB)
  float* tg = gp + (size_t)GCH * B * G4;   // [B][H]

  void* args[] = {(void*)&x, (void*)&h0, (void*)&c0, (void*)&hebb,
                  (void*)&wh, (void*)&wx, (void*)&bias, (void*)&alpha,
                  (void*)&eta, (void*)&out, (void*)&hout,
                  (void*)&pp, (void*)&gp, (void*)&tg};
  hipError_t err = hipLaunchCooperativeKernel(
      (const void*)k_coop, dim3(NBLK), dim3(256), args, 0, stream);
  if (err != hipSuccess) {
    // Fallback: same phases as three plain launches.
    k_p1<<<NBLK, 256, 0, stream>>>(x, h0, wh, wx, alpha, hebb, gp, pp);
    k_p2<<<(B * H) / 256, 256, 0, stream>>>(gp, pp, bias, c0, out, tg);
    k_p3<<<NBLK, 256, 0, stream>>>(hebb, h0, tg, eta, hout);
  }
}

// Round 4
// 316.313 us; speedup vs baseline: 1.7389x; 1.7389x over previous
//
#include <hip/hip_runtime.h>
#include <math.h>

#define B 32
#define D 512
#define H 1024
#define G4 4096      // 4*H
#define PCH 64       // plastic i-chunks (16 i each) -> 2048 blocks
#define GCH 48       // gate i-chunks of 32: 32 cover h (1024), 16 cover x (512)

typedef float f4v __attribute__((ext_vector_type(4)));

// ---------------------------------------------------------------------------
// plastic partials: pp[c][b][h] = sum_{i in chunk c} h0[b,i]*alpha[i,h]*Hebb0[b,i,h]
// 2048 blocks. MLP forced: 16 float4 loads held live in registers per batch.
__global__ __launch_bounds__(256) void k_plastic(
    const float* __restrict__ h0, const float* __restrict__ alpha,
    const float* __restrict__ hebb, float* __restrict__ pp) {
  int blk = blockIdx.x;
  int b = blk >> 6;          // / PCH
  int c = blk & (PCH - 1);
  int h4 = threadIdx.x * 4;
  int i0 = c * (H / PCH);    // 16 i's per chunk
  const float* hb = hebb + (size_t)b * H * H;
  float4 acc = make_float4(0.f, 0.f, 0.f, 0.f);
#pragma unroll
  for (int half = 0; half < 2; ++half) {
    int ib = i0 + half * 8;
    float4 ev[8], av[8];
    float hv[8];
#pragma unroll
    for (int u = 0; u < 8; ++u)
      ev[u] = *(const float4*)(hb + (size_t)(ib + u) * H + h4);
#pragma unroll
    for (int u = 0; u < 8; ++u)
      av[u] = *(const float4*)(alpha + (size_t)(ib + u) * H + h4);
#pragma unroll
    for (int u = 0; u < 8; ++u) hv[u] = h0[b * H + ib + u];
#pragma unroll
    for (int u = 0; u < 8; ++u) {
      acc.x += hv[u] * av[u].x * ev[u].x;
      acc.y += hv[u] * av[u].y * ev[u].y;
      acc.z += hv[u] * av[u].z * ev[u].z;
      acc.w += hv[u] * av[u].w * ev[u].w;
    }
  }
  *(float4*)(pp + ((size_t)c * B + b) * H + h4) = acc;
}

// ---------------------------------------------------------------------------
// gate partials: gp[c][b][j] = sum_{i in chunk c} in[b,i] * W[i,j]
// grid (16 j-blocks, 48 chunks); thread owns one j, all 32 b. W loads batched 8.
__global__ __launch_bounds__(256) void k_gates(
    const float* __restrict__ h0, const float* __restrict__ x,
    const float* __restrict__ wh, const float* __restrict__ wx,
    float* __restrict__ gp) {
  int j = blockIdx.x * 256 + threadIdx.x;
  int c = blockIdx.y;
  const float* Wp;
  const float* in;
  int i0, ld;
  if (c < 32) { Wp = wh; in = h0; i0 = c * 32; ld = H; }
  else        { Wp = wx; in = x;  i0 = (c - 32) * 32; ld = D; }
  float acc[B];
#pragma unroll
  for (int b = 0; b < B; ++b) acc[b] = 0.f;
#pragma unroll
  for (int uo = 0; uo < 4; ++uo) {
    float w[8];
#pragma unroll
    for (int u = 0; u < 8; ++u)
      w[u] = Wp[(size_t)(i0 + uo * 8 + u) * G4 + j];
#pragma unroll
    for (int u = 0; u < 8; ++u) {
      int i = i0 + uo * 8 + u;
#pragma unroll
      for (int b = 0; b < B; ++b) acc[b] += in[b * ld + i] * w[u];  // uniform -> sgpr
    }
  }
#pragma unroll
  for (int b = 0; b < B; ++b) gp[((size_t)c * B + b) * G4 + j] = acc[b];
}

// ---------------------------------------------------------------------------
// combine: reduce partials, activations. 512 blocks x 64 threads so all CUs
// get work; loads batched (32 and 16 in flight) for MLP.
__global__ __launch_bounds__(64) void k_combine(
    const float* __restrict__ gp, const float* __restrict__ pp,
    const float* __restrict__ bias, const float* __restrict__ c0,
    float* __restrict__ out, float* __restrict__ tg_out) {
  int t = blockIdx.x * 64 + threadIdx.x;    // 0..B*H-1
  int b = t >> 10;
  int h = t & (H - 1);
  float sf = bias[h], si = bias[H + h], so = bias[2 * H + h], sg = bias[3 * H + h];
#pragma unroll
  for (int c8 = 0; c8 < GCH / 8; ++c8) {
    float vf[8], vi[8], vo[8], vg[8];
#pragma unroll
    for (int u = 0; u < 8; ++u) {
      const float* g = gp + ((size_t)(c8 * 8 + u) * B + b) * G4;
      vf[u] = g[h];
      vi[u] = g[H + h];
      vo[u] = g[2 * H + h];
      vg[u] = g[3 * H + h];
    }
#pragma unroll
    for (int u = 0; u < 8; ++u) { sf += vf[u]; si += vi[u]; so += vo[u]; sg += vg[u]; }
  }
#pragma unroll
  for (int c16 = 0; c16 < PCH / 16; ++c16) {
    float vp[16];
#pragma unroll
    for (int u = 0; u < 16; ++u)
      vp[u] = pp[((size_t)(c16 * 16 + u) * B + b) * H + h];
#pragma unroll
    for (int u = 0; u < 16; ++u) sg += vp[u];
  }
  float fg = 1.f / (1.f + expf(-sf));
  float ig = 1.f / (1.f + expf(-si));
  float og = 1.f / (1.f + expf(-so));
  float tgv = tanhf(sg);
  float c1 = fg * c0[t] + ig * tgv;
  float h1 = og * tanhf(c1);
  out[t] = h1;                 // h1 block
  out[B * H + t] = c1;         // c1 block
  tg_out[t] = tgv;
}

// ---------------------------------------------------------------------------
// Hebb update: out[b,h,i] = clip(Hebb0[b,h,i] + eta*h0[b,h]*tg[b,i], -1, 1)
// 4096 blocks; 8 rows per block, all 8 row-loads held live -> 8-deep MLP.
// Nontemporal stores keep Hebb1 from evicting the L3-warm Hebb0 reads.
__global__ __launch_bounds__(256) void k_hebb(
    const float* __restrict__ hebb, const float* __restrict__ h0,
    const float* __restrict__ tg, const float* __restrict__ eta,
    float* __restrict__ out) {
  int blk = blockIdx.x;          // 0 .. B*128-1
  int b = blk >> 7;
  int hg = blk & 127;            // h-group of 8 rows
  int t4 = threadIdx.x * 4;
  float4 tv = *(const float4*)(tg + b * H + t4);
  float e = eta[0];
  size_t base = ((size_t)b * H + (size_t)hg * 8) * H + t4;
  const float* src = hebb + base;
  float* dst = out + base;
  float4 v[8];
  float s[8];
#pragma unroll
  for (int r = 0; r < 8; ++r)
    v[r] = *(const float4*)(src + (size_t)r * H);
#pragma unroll
  for (int r = 0; r < 8; ++r)
    s[r] = e * h0[b * H + hg * 8 + r];     // wave-uniform scalar
#pragma unroll
  for (int r = 0; r < 8; ++r) {
    f4v rr;
    rr.x = fminf(fmaxf(v[r].x + s[r] * tv.x, -1.f), 1.f);
    rr.y = fminf(fmaxf(v[r].y + s[r] * tv.y, -1.f), 1.f);
    rr.z = fminf(fmaxf(v[r].z + s[r] * tv.z, -1.f), 1.f);
    rr.w = fminf(fmaxf(v[r].w + s[r] * tv.w, -1.f), 1.f);
    __builtin_nontemporal_store(rr, (f4v*)(dst + (size_t)r * H));
  }
}

extern "C" void kernel_launch(void* const* d_in, const int* in_sizes, int n_in,
                              void* d_out, int out_size, void* d_ws, size_t ws_size,
                              hipStream_t stream) {
  const float* x     = (const float*)d_in[0];
  const float* h0    = (const float*)d_in[1];
  const float* c0    = (const float*)d_in[2];
  const float* hebb  = (const float*)d_in[3];
  const float* wh    = (const float*)d_in[4];
  const float* wx    = (const float*)d_in[5];
  const float* bias  = (const float*)d_in[6];
  const float* alpha = (const float*)d_in[7];
  const float* eta   = (const float*)d_in[8];
  float* out = (float*)d_out;
  float* ws  = (float*)d_ws;

  float* pp = ws;                          // [PCH][B][H]   = 2,097,152 floats (8 MB)
  float* gp = pp + (size_t)PCH * B * H;    // [GCH][B][4H]  = 6,291,456 floats (24 MB)
  float* tg = gp + (size_t)GCH * B * G4;   // [B][H]

  k_plastic<<<B * PCH, 256, 0, stream>>>(h0, alpha, hebb, pp);
  k_gates<<<dim3(16, GCH), 256, 0, stream>>>(h0, x, wh, wx, gp);
  k_combine<<<(B * H) / 64, 64, 0, stream>>>(gp, pp, bias, c0, out, tg);
  k_hebb<<<B * 128, 256, 0, stream>>>(hebb, h0, tg, eta, out + 2 * B * H);
}

// Round 6
// 297.517 us; speedup vs baseline: 1.8488x; 1.0632x over previous
//
#include <hip/hip_runtime.h>
#include <math.h>

#define B 32
#define D 512
#define H 1024
#define G4 4096      // 4*H
#define PCH 32       // plastic i-chunks (32 i each)  -> 1024 plastic blocks
#define GCH 24       // gate i-chunks of 64: 16 cover h (1024), 8 cover x (512)
#define NGATE (16 * GCH)   // 384 gate blocks

typedef float f4v __attribute__((ext_vector_type(4)));

// ---------------------------------------------------------------------------
// Fused partials. Blocks [0,NGATE): gate partials; [NGATE,NGATE+1024): plastic.
// Gate blocks dispatched first (heaviest per block), plastic flood follows.
__global__ __launch_bounds__(256) void k_pg(
    const float* __restrict__ h0, const float* __restrict__ x,
    const float* __restrict__ wh, const float* __restrict__ wx,
    const float* __restrict__ alpha, const float* __restrict__ hebb,
    float* __restrict__ gp, float* __restrict__ pp) {
  int blk = blockIdx.x;
  int tid = threadIdx.x;
  if (blk < NGATE) {
    // ---- gate partial: gp[c][b][j] = sum_{i in chunk c} in[b,i]*W[i,j] ----
    int c = blk % GCH;
    int j = (blk / GCH) * 256 + tid;
    const float* Wp;
    const float* in;
    int i0, ld;
    if (c < 16) { Wp = wh; in = h0; i0 = c * 64; ld = H; }
    else        { Wp = wx; in = x;  i0 = (c - 16) * 64; ld = D; }
    float acc[B];
#pragma unroll
    for (int b = 0; b < B; ++b) acc[b] = 0.f;
#pragma unroll
    for (int uo = 0; uo < 8; ++uo) {
      float w[8];
#pragma unroll
      for (int u = 0; u < 8; ++u)
        w[u] = Wp[(size_t)(i0 + uo * 8 + u) * G4 + j];   // 8 loads in flight
#pragma unroll
      for (int u = 0; u < 8; ++u) {
        int i = i0 + uo * 8 + u;
#pragma unroll
        for (int b = 0; b < B; ++b) acc[b] += in[b * ld + i] * w[u];  // uniform -> sgpr
      }
    }
#pragma unroll
    for (int b = 0; b < B; ++b) gp[((size_t)c * B + b) * G4 + j] = acc[b];
  } else {
    // ---- plastic partial: pp[c][b][h] = sum_{i in chunk} h0*alpha*Hebb0 ----
    int p = blk - NGATE;
    int b = p & (B - 1);       // c-major: same-c blocks adjacent -> alpha L2 reuse
    int c = p >> 5;
    int h4 = tid * 4;
    int i0 = c * (H / PCH);    // 32 i's per chunk
    const float* hb = hebb + (size_t)b * H * H;
    float4 acc = make_float4(0.f, 0.f, 0.f, 0.f);
#pragma unroll
    for (int quad = 0; quad < 4; ++quad) {
      int ib = i0 + quad * 8;
      float4 ev[8], av[8];
      float hv[8];
#pragma unroll
      for (int u = 0; u < 8; ++u)
        ev[u] = *(const float4*)(hb + (size_t)(ib + u) * H + h4);    // 16 loads
#pragma unroll
      for (int u = 0; u < 8; ++u)
        av[u] = *(const float4*)(alpha + (size_t)(ib + u) * H + h4); // in flight
#pragma unroll
      for (int u = 0; u < 8; ++u) hv[u] = h0[b * H + ib + u];
#pragma unroll
      for (int u = 0; u < 8; ++u) {
        acc.x += hv[u] * av[u].x * ev[u].x;
        acc.y += hv[u] * av[u].y * ev[u].y;
        acc.z += hv[u] * av[u].z * ev[u].z;
        acc.w += hv[u] * av[u].w * ev[u].w;
      }
    }
    *(float4*)(pp + ((size_t)c * B + b) * H + h4) = acc;
  }
}

// ---------------------------------------------------------------------------
// combine: reduce partials + activations. 128 blocks x 256 threads (full-wave
// coalescing); loads explicitly batched 8-deep for MLP.
__global__ __launch_bounds__(256) void k_combine(
    const float* __restrict__ gp, const float* __restrict__ pp,
    const float* __restrict__ bias, const float* __restrict__ c0,
    float* __restrict__ out, float* __restrict__ tg_out) {
  int t = blockIdx.x * 256 + threadIdx.x;   // 0..B*H-1
  int b = t >> 10;
  int h = t & (H - 1);
  float sf = bias[h], si = bias[H + h], so = bias[2 * H + h], sg = bias[3 * H + h];
#pragma unroll
  for (int c8 = 0; c8 < GCH / 8; ++c8) {
    float vf[8], vi[8], vo[8], vg[8];
#pragma unroll
    for (int u = 0; u < 8; ++u) {
      const float* g = gp + ((size_t)(c8 * 8 + u) * B + b) * G4;
      vf[u] = g[h]; vi[u] = g[H + h]; vo[u] = g[2 * H + h]; vg[u] = g[3 * H + h];
    }
#pragma unroll
    for (int u = 0; u < 8; ++u) { sf += vf[u]; si += vi[u]; so += vo[u]; sg += vg[u]; }
  }
#pragma unroll
  for (int c8 = 0; c8 < PCH / 8; ++c8) {
    float vp[8];
#pragma unroll
    for (int u = 0; u < 8; ++u)
      vp[u] = pp[((size_t)(c8 * 8 + u) * B + b) * H + h];
#pragma unroll
    for (int u = 0; u < 8; ++u) sg += vp[u];
  }
  float fg = 1.f / (1.f + expf(-sf));
  float ig = 1.f / (1.f + expf(-si));
  float og = 1.f / (1.f + expf(-so));
  float tgv = tanhf(sg);
  float c1 = fg * c0[t] + ig * tgv;
  float h1 = og * tanhf(c1);
  out[t] = h1;                 // h1 block
  out[B * H + t] = c1;         // c1 block
  tg_out[t] = tgv;
}

// ---------------------------------------------------------------------------
// Hebb update: all 8 row-loads batched BEFORE any store (stores share vmcnt
// with loads on CDNA -- interleaving load/store chains serializes at HBM
// latency). NT stores: Hebb1 is never re-read.
__global__ __launch_bounds__(256) void k_hebb(
    const float* __restrict__ hebb, const float* __restrict__ h0,
    const float* __restrict__ tg, const float* __restrict__ eta,
    float* __restrict__ out) {
  int blk = blockIdx.x;          // 0 .. B*128-1
  int b = blk >> 7;
  int hg = blk & 127;            // h-group of 8 rows
  int t4 = threadIdx.x * 4;
  float4 tv = *(const float4*)(tg + b * H + t4);
  float e = eta[0];
  size_t base = ((size_t)b * H + (size_t)hg * 8) * H + t4;
  const float* src = hebb + base;
  float* dst = out + base;
  float4 v[8];
  float s[8];
#pragma unroll
  for (int r = 0; r < 8; ++r)
    v[r] = *(const float4*)(src + (size_t)r * H);        // 8 loads in flight
#pragma unroll
  for (int r = 0; r < 8; ++r)
    s[r] = e * h0[b * H + hg * 8 + r];                   // wave-uniform scalar
#pragma unroll
  for (int r = 0; r < 8; ++r) {
    f4v rr;
    rr.x = fminf(fmaxf(v[r].x + s[r] * tv.x, -1.f), 1.f);
    rr.y = fminf(fmaxf(v[r].y + s[r] * tv.y, -1.f), 1.f);
    rr.z = fminf(fmaxf(v[r].z + s[r] * tv.z, -1.f), 1.f);
    rr.w = fminf(fmaxf(v[r].w + s[r] * tv.w, -1.f), 1.f);
    __builtin_nontemporal_store(rr, (f4v*)(dst + (size_t)r * H));
  }
}

extern "C" void kernel_launch(void* const* d_in, const int* in_sizes, int n_in,
                              void* d_out, int out_size, void* d_ws, size_t ws_size,
                              hipStream_t stream) {
  const float* x     = (const float*)d_in[0];
  const float* h0    = (const float*)d_in[1];
  const float* c0    = (const float*)d_in[2];
  const float* hebb  = (const float*)d_in[3];
  const float* wh    = (const float*)d_in[4];
  const float* wx    = (const float*)d_in[5];
  const float* bias  = (const float*)d_in[6];
  const float* alpha = (const float*)d_in[7];
  const float* eta   = (const float*)d_in[8];
  float* out = (float*)d_out;
  float* ws  = (float*)d_ws;

  float* pp = ws;                          // [PCH][B][H]   = 1,048,576 floats (4 MB)
  float* gp = pp + (size_t)PCH * B * H;    // [GCH][B][4H]  = 3,145,728 floats (12 MB)
  float* tg = gp + (size_t)GCH * B * G4;   // [B][H]

  k_pg<<<NGATE + B * PCH, 256, 0, stream>>>(h0, x, wh, wx, alpha, hebb, gp, pp);
  k_combine<<<(B * H) / 256, 256, 0, stream>>>(gp, pp, bias, c0, out, tg);
  k_hebb<<<B * 128, 256, 0, stream>>>(hebb, h0, tg, eta, out + 2 * B * H);
}